// Round 5
// baseline (153.156 us; speedup 1.0000x reference)
//
#include <hip/hip_runtime.h>

// R12: geometry = R8 (2048 x 64, one wave per WG, 2 rows per wave,
// half-wave per row) but with per-wave instruction count cut ~2.5x.
// Theory: R8-R11b all ~31us with utterly different memory plans ->
// pin is per-wave serial issue count (~3500 LDS/VMEM/VALU ops), not
// latency placement. Changes:
//  - token loop: direct-global float4, 4 tokens/iter (5 VMEM per 4
//    tokens vs 16 LDS per 4 tokens; no cont staging, no LDS round-trip)
//  - cat pass: wide int4 register loads, field = (elem idx) mod 5
//    attribution, L-gated blocks; sums for fields 0-2, predicated LDS
//    atomics for fields 3-4; cat_c int4 = 2 tokens, compile-time fields
//  - LDS down to 2.3 KB (hist + sAcc + sPool); weights from global/L1
//    (R10 proved LDS-vs-global for weights is neutral)
//  - dual-row unified tail + fc1 kept verbatim from R11b
// Algebra unchanged: histogram-weighted table sums, binary-vocab counts =
// index sums, pooling commutes with the 32x32 second layers.

#define BDIM 64

__global__ __launch_bounds__(BDIM, 2)
void mlpreg_kernel(const float* __restrict__ cont_p,
                   const float* __restrict__ cont_c,
                   const int* __restrict__ cat_p,
                   const int* __restrict__ cat_c,
                   const int* __restrict__ lengths,
                   const float* __restrict__ w_p1, const float* __restrict__ b_p1,
                   const float* __restrict__ w_p2, const float* __restrict__ b_p2,
                   const float* __restrict__ w_c1, const float* __restrict__ b_c1,
                   const float* __restrict__ w_c2, const float* __restrict__ b_c2,
                   const float* __restrict__ emb_g,  const float* __restrict__ emb_k,
                   const float* __restrict__ emb_pr, const float* __restrict__ emb_j,
                   const float* __restrict__ emb_r,  const float* __restrict__ emb_pl,
                   const float* __restrict__ emb_a,
                   const float* __restrict__ w_fc1, const float* __restrict__ b_fc1,
                   const float* __restrict__ w_fc2, const float* __restrict__ b_fc2,
                   float* __restrict__ out)
{
    constexpr int S = 256;
    __shared__ int   hist[2][96];    // job@0(11) rep@11(34) place@45(19) add@64(31)
    __shared__ float sAcc[2][64];    // [row][aP(32) aC(32)] pooled layer1
    __shared__ float sPool[2][128];  // [row][ep ec hp hc]

    const int lane = threadIdx.x;
    const int ch = lane & 31, h = lane >> 5;
    const int b0 = blockIdx.x * 2, b1 = b0 + 1;

    int L0 = lengths[b0]; L0 = (L0 < 1) ? 1 : (L0 > S ? S : L0);
    int L1 = lengths[b1]; L1 = (L1 < 1) ? 1 : (L1 > S ? S : L1);
    const float L0f = (float)L0, L1f = (float)L1;
    const float invL0 = 1.0f / L0f, invL1 = 1.0f / L1f;

    // ---- small-weight register preloads (independent, issue early) ----
    const float wp0 = w_p1[ch], wp1 = w_p1[32 + ch], wp2 = w_p1[64 + ch], bp = b_p1[ch];
    const float wc0 = w_c1[ch], wc1 = w_c1[32 + ch], bc = b_c1[ch];
    const float eg0 = emb_g[ch],  eg1 = emb_g[32 + ch];
    const float ek0 = emb_k[ch],  ek1 = emb_k[32 + ch];
    const float er0 = emb_pr[ch], er1 = emb_pr[32 + ch];
    const float bias2 = h ? b_c2[ch] : b_p2[ch];
    const float bf1 = b_fc1[lane];
    const float2 wf2 = *(const float2*)&w_fc2[2 * lane];
    const float bq0 = b_fc2[0], bq1 = b_fc2[1];

    // zero hist (same-wave ordering protects the later atomics)
    { int i = lane;  ((int*)hist)[i] = 0;
      i += 64;       ((int*)hist)[i] = 0;
      i += 64;       ((int*)hist)[i] = 0; }

    // ---- cat wide loads, L-gated blocks, all issued upfront ----
    const int4* KP0 = (const int4*)(cat_p + (size_t)b0 * (S * 5));
    const int4* KP1 = (const int4*)(cat_p + (size_t)b1 * (S * 5));
    const int4* KC0 = (const int4*)(cat_c + (size_t)b0 * (S * 2));
    const int4* KC1 = (const int4*)(cat_c + (size_t)b1 * (S * 2));
    const int lim_p0 = 5 * L0, lim_p1 = 5 * L1;
    const int lim_c0 = 2 * L0, lim_c1 = 2 * L1;
    int4 qp0[5], qp1[5], qc0[2], qc1[2];
    #pragma unroll
    for (int j = 0; j < 5; ++j) {
        if (256 * j < lim_p0) qp0[j] = KP0[lane + 64 * j];
        if (256 * j < lim_p1) qp1[j] = KP1[lane + 64 * j];
    }
    #pragma unroll
    for (int j = 0; j < 2; ++j) {
        if (256 * j < lim_c0) qc0[j] = KC0[lane + 64 * j];
        if (256 * j < lim_c1) qc1[j] = KC1[lane + 64 * j];
    }

    // ---- token relu-MLP: half-wave h owns row b0+h, DIRECT global float4,
    //      4 tokens per iter (cat loads above stay in flight under this) ----
    {
        const int   row  = h ? b1 : b0;
        const int   Lr   = h ? L1 : L0;
        const float invr = h ? invL1 : invL0;
        const float4* tp4 = (const float4*)(cont_p + (size_t)row * 768);
        const float4* tc4 = (const float4*)(cont_c + (size_t)row * 512);
        float aP = 0.f, aC = 0.f;
        const int gf = Lr >> 2;
        #pragma unroll 4
        for (int g = 0; g < gf; ++g) {
            float4 a  = tp4[3 * g], bb = tp4[3 * g + 1], cc = tp4[3 * g + 2];
            float4 d  = tc4[2 * g], ee = tc4[2 * g + 1];
            float p0 = fmaxf(fmaf(a.x,  wp0, fmaf(a.y,  wp1, fmaf(a.z,  wp2, bp))), 0.f);
            float p1 = fmaxf(fmaf(a.w,  wp0, fmaf(bb.x, wp1, fmaf(bb.y, wp2, bp))), 0.f);
            float p2 = fmaxf(fmaf(bb.z, wp0, fmaf(bb.w, wp1, fmaf(cc.x, wp2, bp))), 0.f);
            float p3 = fmaxf(fmaf(cc.y, wp0, fmaf(cc.z, wp1, fmaf(cc.w, wp2, bp))), 0.f);
            aP += (p0 + p1) + (p2 + p3);
            float q0 = fmaxf(fmaf(d.x,  wc0, fmaf(d.y,  wc1, bc)), 0.f);
            float q1 = fmaxf(fmaf(d.z,  wc0, fmaf(d.w,  wc1, bc)), 0.f);
            float q2 = fmaxf(fmaf(ee.x, wc0, fmaf(ee.y, wc1, bc)), 0.f);
            float q3 = fmaxf(fmaf(ee.z, wc0, fmaf(ee.w, wc1, bc)), 0.f);
            aC += (q0 + q1) + (q2 + q3);
        }
        const int rem = Lr & 3;
        if (rem) {
            const float* tp = (const float*)(tp4 + 3 * gf);
            const float* tc = (const float*)(tc4 + 2 * gf);
            for (int r = 0; r < rem; ++r) {
                aP += fmaxf(fmaf(tp[3*r], wp0, fmaf(tp[3*r+1], wp1, fmaf(tp[3*r+2], wp2, bp))), 0.f);
                aC += fmaxf(fmaf(tc[2*r], wc0, fmaf(tc[2*r+1], wc1, bc)), 0.f);
            }
        }
        sAcc[h][ch]      = aP * invr;
        sAcc[h][32 + ch] = aC * invr;
    }

    // ---- cat processing from registers: field = elem mod 5 ----
    int sg0 = 0, sk0 = 0, sp0 = 0, sg1 = 0, sk1 = 0, sp1 = 0;
    const int m0 = (lane << 2) % 5;     // field of component 0 at j=0
    #pragma unroll
    for (int j = 0; j < 5; ++j) {
        int mj = m0 + j; if (mj >= 5) mj -= 5;
        if (256 * j < lim_p0) {
            const int base = 4 * lane + 256 * j;
            const int v[4] = {qp0[j].x, qp0[j].y, qp0[j].z, qp0[j].w};
            #pragma unroll
            for (int c = 0; c < 4; ++c) {
                int f = mj + c; if (f >= 5) f -= 5;
                const bool val = (base + c) < lim_p0;
                const int vv = v[c];
                sg0 += (val && f == 0) ? vv : 0;
                sk0 += (val && f == 1) ? vv : 0;
                sp0 += (val && f == 2) ? vv : 0;
                if (val && f >= 3) atomicAdd(&hist[0][(f == 4 ? 11 : 0) + vv], 1);
            }
        }
        if (256 * j < lim_p1) {
            const int base = 4 * lane + 256 * j;
            const int v[4] = {qp1[j].x, qp1[j].y, qp1[j].z, qp1[j].w};
            #pragma unroll
            for (int c = 0; c < 4; ++c) {
                int f = mj + c; if (f >= 5) f -= 5;
                const bool val = (base + c) < lim_p1;
                const int vv = v[c];
                sg1 += (val && f == 0) ? vv : 0;
                sk1 += (val && f == 1) ? vv : 0;
                sp1 += (val && f == 2) ? vv : 0;
                if (val && f >= 3) atomicAdd(&hist[1][(f == 4 ? 11 : 0) + vv], 1);
            }
        }
    }
    // cat_c: int4 = 2 tokens, fields compile-time (place, add, place, add)
    #pragma unroll
    for (int j = 0; j < 2; ++j) {
        const int base = 4 * lane + 256 * j;
        if (256 * j < lim_c0) {
            if (base     < lim_c0) atomicAdd(&hist[0][45 + qc0[j].x], 1);
            if (base + 1 < lim_c0) atomicAdd(&hist[0][64 + qc0[j].y], 1);
            if (base + 2 < lim_c0) atomicAdd(&hist[0][45 + qc0[j].z], 1);
            if (base + 3 < lim_c0) atomicAdd(&hist[0][64 + qc0[j].w], 1);
        }
        if (256 * j < lim_c1) {
            if (base     < lim_c1) atomicAdd(&hist[1][45 + qc1[j].x], 1);
            if (base + 1 < lim_c1) atomicAdd(&hist[1][64 + qc1[j].y], 1);
            if (base + 2 < lim_c1) atomicAdd(&hist[1][45 + qc1[j].z], 1);
            if (base + 3 < lim_c1) atomicAdd(&hist[1][64 + qc1[j].w], 1);
        }
    }
    #pragma unroll
    for (int d = 32; d; d >>= 1) {
        sg0 += __shfl_xor(sg0, d); sk0 += __shfl_xor(sk0, d); sp0 += __shfl_xor(sp0, d);
        sg1 += __shfl_xor(sg1, d); sk1 += __shfl_xor(sk1, d); sp1 += __shfl_xor(sp1, d);
    }
    __syncthreads();   // single-wave: orders sAcc/hist writes vs tail reads

    // ---- tail: unified halves (h=0 p-side, h=1 c-side), dual-row FMA ----
    float A0, A1;
    {
        float fg0 = (float)sg0, fk0 = (float)sk0, fp0 = (float)sp0;
        float fg1 = (float)sg1, fk1 = (float)sk1, fp1 = (float)sp1;
        A0 = fmaf(L0f - fg0, eg0, fg0 * eg1) + fmaf(L0f - fk0, ek0, fk0 * ek1)
           + fmaf(L0f - fp0, er0, fp0 * er1);
        A1 = fmaf(L1f - fg1, eg0, fg1 * eg1) + fmaf(L1f - fk1, ek0, fk1 * ek1)
           + fmaf(L1f - fp1, er0, fp1 * er1);
        if (h) { A0 = 0.f; A1 = 0.f; }
    }
    {
        // h=0: job(11)+rep(34) over hist[0..44]; h=1: place(19)+add(31) over hist[45..94]
        const float* tA = h ? emb_pl : emb_j;
        const float* tB = h ? emb_a  : emb_r;
        const int nA = h ? 19 : 11;
        const int nT = h ? 50 : 45;
        const int hb = h ? 45 : 0;
        #pragma unroll 5
        for (int r = 0; r < nT; ++r) {
            const float* p = (r < nA) ? (tA + (r << 5)) : (tB + ((r - nA) << 5));
            float w = p[ch];
            A0 = fmaf((float)hist[0][hb + r], w, A0);
            A1 = fmaf((float)hist[1][hb + r], w, A1);
        }
        const float sc = h ? 0.5f : 0.2f;
        sPool[0][(h << 5) + ch] = A0 * (invL0 * sc);
        sPool[1][(h << 5) + ch] = A1 * (invL1 * sc);
    }
    {
        // unified 32x32 second layer, dual-row: one weight load -> 2 FMAs
        const float* W2 = h ? w_c2 : w_p2;
        const float* a0 = &sAcc[0][h << 5];
        const float* a1 = &sAcc[1][h << 5];
        float v0 = bias2, v1 = bias2;
        #pragma unroll 8
        for (int k = 0; k < 32; ++k) {
            float w = W2[(k << 5) + ch];
            v0 = fmaf(a0[k], w, v0);
            v1 = fmaf(a1[k], w, v1);
        }
        sPool[0][64 + (h << 5) + ch] = v0;
        sPool[1][64 + (h << 5) + ch] = v1;
    }
    __syncthreads();   // sPool ready

    // ---- fc1 (one output per lane, dual-row, global weights) + fc2 ----
    {
        const float* P0 = sPool[0];
        const float* P1 = sPool[1];
        float x0 = bf1, y0 = 0.f, x1 = bf1, y1 = 0.f;
        #pragma unroll 8
        for (int k = 0; k < 128; k += 2) {
            float w0 = w_fc1[(size_t)k * 64 + lane];
            float w1 = w_fc1[(size_t)(k + 1) * 64 + lane];
            float2 u0 = *(const float2*)&P0[k];
            float2 u1 = *(const float2*)&P1[k];
            x0 = fmaf(u0.x, w0, x0); y0 = fmaf(u0.y, w1, y0);
            x1 = fmaf(u1.x, w0, x1); y1 = fmaf(u1.y, w1, y1);
        }
        float h0v = fmaxf(x0 + y0, 0.f);
        float h1v = fmaxf(x1 + y1, 0.f);
        float q00 = h0v * wf2.x, q01 = h0v * wf2.y;
        float q10 = h1v * wf2.x, q11 = h1v * wf2.y;
        #pragma unroll
        for (int d = 32; d; d >>= 1) {
            q00 += __shfl_xor(q00, d); q01 += __shfl_xor(q01, d);
            q10 += __shfl_xor(q10, d); q11 += __shfl_xor(q11, d);
        }
        if (lane == 0) {
            float4 o4;
            o4.x = fmaxf(q00 + bq0, 0.f);
            o4.y = fmaxf(q01 + bq1, 0.f);
            o4.z = fmaxf(q10 + bq0, 0.f);
            o4.w = fmaxf(q11 + bq1, 0.f);
            *(float4*)&out[(size_t)b0 * 2] = o4;   // rows b0,b1; 16B-aligned
        }
    }
}

extern "C" void kernel_launch(void* const* d_in, const int* in_sizes, int n_in,
                              void* d_out, int out_size, void* d_ws, size_t ws_size,
                              hipStream_t stream) {
    const float* cont_p = (const float*)d_in[0];
    const float* cont_c = (const float*)d_in[1];
    const int*   cat_p  = (const int*)d_in[2];
    const int*   cat_c  = (const int*)d_in[3];
    const int*   lens   = (const int*)d_in[4];
    const float* w_p1   = (const float*)d_in[5];
    const float* b_p1   = (const float*)d_in[6];
    const float* w_p2   = (const float*)d_in[7];
    const float* b_p2   = (const float*)d_in[8];
    const float* w_c1   = (const float*)d_in[9];
    const float* b_c1   = (const float*)d_in[10];
    const float* w_c2   = (const float*)d_in[11];
    const float* b_c2   = (const float*)d_in[12];
    const float* emb_g  = (const float*)d_in[13];
    const float* emb_k  = (const float*)d_in[14];
    const float* emb_pr = (const float*)d_in[15];
    const float* emb_j  = (const float*)d_in[16];
    const float* emb_r  = (const float*)d_in[17];
    const float* emb_pl = (const float*)d_in[18];
    const float* emb_a  = (const float*)d_in[19];
    const float* w_fc1  = (const float*)d_in[20];
    const float* b_fc1  = (const float*)d_in[21];
    const float* w_fc2  = (const float*)d_in[22];
    const float* b_fc2  = (const float*)d_in[23];
    float* out = (float*)d_out;

    hipLaunchKernelGGL(mlpreg_kernel, dim3(2048), dim3(BDIM), 0, stream,
                       cont_p, cont_c, cat_p, cat_c, lens,
                       w_p1, b_p1, w_p2, b_p2, w_c1, b_c1, w_c2, b_c2,
                       emb_g, emb_k, emb_pr, emb_j, emb_r, emb_pl, emb_a,
                       w_fc1, b_fc1, w_fc2, b_fc2, out);
}

// Round 6
// 143.481 us; speedup vs baseline: 1.0674x; 1.0674x over previous
//
#include <hip/hip_runtime.h>

// R13: combine the proven-fast half of R8 (cont features staged to LDS as
// wide per-lane coalesced bursts -> 31us) with the proven half of R12
// (cat features as wide upfront int4 register loads), and upgrade cont
// staging to __builtin_amdgcn_global_load_lds width=16 (m97 pattern: no
// VGPR round-trip, all staging VMEM in flight at once).
// Theory: all rounds show time ~= FETCH_SIZE / ~330GB/s with HBM at 4% ->
// latency-limited by bytes-in-flight on an L3-cold system (harness fill
// evicts L3 every iter). Achieved BW = outstanding_bytes/latency, so the
// fix is issuing ALL per-row loads as wide coalesced ops before any use:
// ~24 wide VMEM/wave in flight (10 global_load_lds chunks + 14 int4).
// Geometry: R8/R12's 2048 x 64 (1 wave, 2 rows/wave, half-wave per row).
// LDS 12.5KB: cont rows + hist + acc + pool. Compute = R12 verbatim with
// token loop re-pointed at LDS (broadcast ds_read_b128).
// Algebra unchanged: histogram-weighted table sums, binary-vocab counts =
// index sums, pooling commutes with the 32x32 second layers.

#define BDIM 64

__device__ __forceinline__ void gld16(const void* g, void* l) {
    __builtin_amdgcn_global_load_lds((__attribute__((address_space(1))) void*)g,
                                     (__attribute__((address_space(3))) void*)l,
                                     16, 0, 0);
}

__global__ __launch_bounds__(BDIM)
void mlpreg_kernel(const float* __restrict__ cont_p,
                   const float* __restrict__ cont_c,
                   const int* __restrict__ cat_p,
                   const int* __restrict__ cat_c,
                   const int* __restrict__ lengths,
                   const float* __restrict__ w_p1, const float* __restrict__ b_p1,
                   const float* __restrict__ w_p2, const float* __restrict__ b_p2,
                   const float* __restrict__ w_c1, const float* __restrict__ b_c1,
                   const float* __restrict__ w_c2, const float* __restrict__ b_c2,
                   const float* __restrict__ emb_g,  const float* __restrict__ emb_k,
                   const float* __restrict__ emb_pr, const float* __restrict__ emb_j,
                   const float* __restrict__ emb_r,  const float* __restrict__ emb_pl,
                   const float* __restrict__ emb_a,
                   const float* __restrict__ w_fc1, const float* __restrict__ b_fc1,
                   const float* __restrict__ w_fc2, const float* __restrict__ b_fc2,
                   float* __restrict__ out)
{
    constexpr int S = 256;
    __shared__ __align__(16) float sPc[2 * 768];   // cont_p rows   6144 B
    __shared__ __align__(16) float sCc[2 * 512];   // cont_c rows   4096 B
    __shared__ int   hist[2][96];                  //  768 B
    __shared__ float sAcc[2][64];                  //  512 B
    __shared__ float sPool[2][128];                // 1024 B
    // total 12544 B

    const int lane = threadIdx.x;
    const int ch = lane & 31, h = lane >> 5;
    const int b0 = blockIdx.x * 2, b1 = b0 + 1;

    int L0 = lengths[b0]; L0 = (L0 < 1) ? 1 : (L0 > S ? S : L0);
    int L1 = lengths[b1]; L1 = (L1 < 1) ? 1 : (L1 > S ? S : L1);
    const float L0f = (float)L0, L1f = (float)L1;
    const float invL0 = 1.0f / L0f, invL1 = 1.0f / L1f;

    // ---- cont staging: global_load_lds 16B, wave-uniform chunk gating ----
    {
        const char* gp0 = (const char*)(cont_p + (size_t)b0 * 768);
        const char* gp1 = (const char*)(cont_p + (size_t)b1 * 768);
        const char* gc0 = (const char*)(cont_c + (size_t)b0 * 512);
        const char* gc1 = (const char*)(cont_c + (size_t)b1 * 512);
        const int bp0 = 12 * L0, bp1 = 12 * L1;   // bytes needed, cont_p
        const int bc0 = 8 * L0,  bc1 = 8 * L1;    // bytes needed, cont_c
        const int lo = 16 * lane;
        #pragma unroll
        for (int j = 0; j < 3; ++j) {
            if (1024 * j < bp0) gld16(gp0 + 1024 * j + lo, (char*)sPc + 1024 * j);
            if (1024 * j < bp1) gld16(gp1 + 1024 * j + lo, (char*)sPc + 3072 + 1024 * j);
        }
        #pragma unroll
        for (int j = 0; j < 2; ++j) {
            if (1024 * j < bc0) gld16(gc0 + 1024 * j + lo, (char*)sCc + 1024 * j);
            if (1024 * j < bc1) gld16(gc1 + 1024 * j + lo, (char*)sCc + 2048 + 1024 * j);
        }
    }

    // ---- cat wide int4 register loads, wave-uniform chunk gating ----
    const int4* KP0 = (const int4*)(cat_p + (size_t)b0 * (S * 5));
    const int4* KP1 = (const int4*)(cat_p + (size_t)b1 * (S * 5));
    const int4* KC0 = (const int4*)(cat_c + (size_t)b0 * (S * 2));
    const int4* KC1 = (const int4*)(cat_c + (size_t)b1 * (S * 2));
    const int lim_p0 = 5 * L0, lim_p1 = 5 * L1;
    const int lim_c0 = 2 * L0, lim_c1 = 2 * L1;
    int4 qp0[5], qp1[5], qc0[2], qc1[2];
    #pragma unroll
    for (int j = 0; j < 5; ++j) {
        if (256 * j < lim_p0) qp0[j] = KP0[lane + 64 * j];
        if (256 * j < lim_p1) qp1[j] = KP1[lane + 64 * j];
    }
    #pragma unroll
    for (int j = 0; j < 2; ++j) {
        if (256 * j < lim_c0) qc0[j] = KC0[lane + 64 * j];
        if (256 * j < lim_c1) qc1[j] = KC1[lane + 64 * j];
    }

    // ---- small-weight register preloads (issue under staging latency) ----
    const float wp0 = w_p1[ch], wp1 = w_p1[32 + ch], wp2 = w_p1[64 + ch], bp = b_p1[ch];
    const float wc0 = w_c1[ch], wc1 = w_c1[32 + ch], bc = b_c1[ch];
    const float eg0 = emb_g[ch],  eg1 = emb_g[32 + ch];
    const float ek0 = emb_k[ch],  ek1 = emb_k[32 + ch];
    const float er0 = emb_pr[ch], er1 = emb_pr[32 + ch];
    const float bias2 = h ? b_c2[ch] : b_p2[ch];
    const float bf1 = b_fc1[lane];
    const float2 wf2 = *(const float2*)&w_fc2[2 * lane];
    const float bq0 = b_fc2[0], bq1 = b_fc2[1];

    // zero hist (same-wave LDS in-order: writes precede later atomics)
    { int i = lane;  ((int*)hist)[i] = 0;
      i += 64;       ((int*)hist)[i] = 0;
      i += 64;       ((int*)hist)[i] = 0; }

    __syncthreads();   // drains vmcnt(0): staging + cat loads complete

    // ---- token relu-MLP: half-wave h owns row b0+h, LDS float4, 4 tok/iter ----
    {
        const int   Lr   = h ? L1 : L0;
        const float invr = h ? invL1 : invL0;
        const float4* tp4 = (const float4*)(sPc + (h ? 768 : 0));
        const float4* tc4 = (const float4*)(sCc + (h ? 512 : 0));
        float aP = 0.f, aC = 0.f;
        const int gf = Lr >> 2;
        #pragma unroll 4
        for (int g = 0; g < gf; ++g) {
            float4 a  = tp4[3 * g], bb = tp4[3 * g + 1], cc = tp4[3 * g + 2];
            float4 d  = tc4[2 * g], ee = tc4[2 * g + 1];
            float p0 = fmaxf(fmaf(a.x,  wp0, fmaf(a.y,  wp1, fmaf(a.z,  wp2, bp))), 0.f);
            float p1 = fmaxf(fmaf(a.w,  wp0, fmaf(bb.x, wp1, fmaf(bb.y, wp2, bp))), 0.f);
            float p2 = fmaxf(fmaf(bb.z, wp0, fmaf(bb.w, wp1, fmaf(cc.x, wp2, bp))), 0.f);
            float p3 = fmaxf(fmaf(cc.y, wp0, fmaf(cc.z, wp1, fmaf(cc.w, wp2, bp))), 0.f);
            aP += (p0 + p1) + (p2 + p3);
            float q0 = fmaxf(fmaf(d.x,  wc0, fmaf(d.y,  wc1, bc)), 0.f);
            float q1 = fmaxf(fmaf(d.z,  wc0, fmaf(d.w,  wc1, bc)), 0.f);
            float q2 = fmaxf(fmaf(ee.x, wc0, fmaf(ee.y, wc1, bc)), 0.f);
            float q3 = fmaxf(fmaf(ee.z, wc0, fmaf(ee.w, wc1, bc)), 0.f);
            aC += (q0 + q1) + (q2 + q3);
        }
        const int rem = Lr & 3;
        if (rem) {
            const float* tp = (const float*)(tp4 + 3 * gf);
            const float* tc = (const float*)(tc4 + 2 * gf);
            for (int r = 0; r < rem; ++r) {
                aP += fmaxf(fmaf(tp[3*r], wp0, fmaf(tp[3*r+1], wp1, fmaf(tp[3*r+2], wp2, bp))), 0.f);
                aC += fmaxf(fmaf(tc[2*r], wc0, fmaf(tc[2*r+1], wc1, bc)), 0.f);
            }
        }
        sAcc[h][ch]      = aP * invr;
        sAcc[h][32 + ch] = aC * invr;
    }

    // ---- cat processing from registers: field = elem mod 5 ----
    int sg0 = 0, sk0 = 0, sp0 = 0, sg1 = 0, sk1 = 0, sp1 = 0;
    const int m0 = (lane << 2) % 5;     // field of component 0 at j=0
    #pragma unroll
    for (int j = 0; j < 5; ++j) {
        int mj = m0 + j; if (mj >= 5) mj -= 5;
        if (256 * j < lim_p0) {
            const int base = 4 * lane + 256 * j;
            const int v[4] = {qp0[j].x, qp0[j].y, qp0[j].z, qp0[j].w};
            #pragma unroll
            for (int c = 0; c < 4; ++c) {
                int f = mj + c; if (f >= 5) f -= 5;
                const bool val = (base + c) < lim_p0;
                const int vv = v[c];
                sg0 += (val && f == 0) ? vv : 0;
                sk0 += (val && f == 1) ? vv : 0;
                sp0 += (val && f == 2) ? vv : 0;
                if (val && f >= 3) atomicAdd(&hist[0][(f == 4 ? 11 : 0) + vv], 1);
            }
        }
        if (256 * j < lim_p1) {
            const int base = 4 * lane + 256 * j;
            const int v[4] = {qp1[j].x, qp1[j].y, qp1[j].z, qp1[j].w};
            #pragma unroll
            for (int c = 0; c < 4; ++c) {
                int f = mj + c; if (f >= 5) f -= 5;
                const bool val = (base + c) < lim_p1;
                const int vv = v[c];
                sg1 += (val && f == 0) ? vv : 0;
                sk1 += (val && f == 1) ? vv : 0;
                sp1 += (val && f == 2) ? vv : 0;
                if (val && f >= 3) atomicAdd(&hist[1][(f == 4 ? 11 : 0) + vv], 1);
            }
        }
    }
    // cat_c: int4 = 2 tokens, fields compile-time (place, add, place, add)
    #pragma unroll
    for (int j = 0; j < 2; ++j) {
        const int base = 4 * lane + 256 * j;
        if (256 * j < lim_c0) {
            if (base     < lim_c0) atomicAdd(&hist[0][45 + qc0[j].x], 1);
            if (base + 1 < lim_c0) atomicAdd(&hist[0][64 + qc0[j].y], 1);
            if (base + 2 < lim_c0) atomicAdd(&hist[0][45 + qc0[j].z], 1);
            if (base + 3 < lim_c0) atomicAdd(&hist[0][64 + qc0[j].w], 1);
        }
        if (256 * j < lim_c1) {
            if (base     < lim_c1) atomicAdd(&hist[1][45 + qc1[j].x], 1);
            if (base + 1 < lim_c1) atomicAdd(&hist[1][64 + qc1[j].y], 1);
            if (base + 2 < lim_c1) atomicAdd(&hist[1][45 + qc1[j].z], 1);
            if (base + 3 < lim_c1) atomicAdd(&hist[1][64 + qc1[j].w], 1);
        }
    }
    #pragma unroll
    for (int d = 32; d; d >>= 1) {
        sg0 += __shfl_xor(sg0, d); sk0 += __shfl_xor(sk0, d); sp0 += __shfl_xor(sp0, d);
        sg1 += __shfl_xor(sg1, d); sk1 += __shfl_xor(sk1, d); sp1 += __shfl_xor(sp1, d);
    }
    __syncthreads();   // orders sAcc/hist writes vs tail reads

    // ---- tail: unified halves (h=0 p-side, h=1 c-side), dual-row FMA ----
    float A0, A1;
    {
        float fg0 = (float)sg0, fk0 = (float)sk0, fp0 = (float)sp0;
        float fg1 = (float)sg1, fk1 = (float)sk1, fp1 = (float)sp1;
        A0 = fmaf(L0f - fg0, eg0, fg0 * eg1) + fmaf(L0f - fk0, ek0, fk0 * ek1)
           + fmaf(L0f - fp0, er0, fp0 * er1);
        A1 = fmaf(L1f - fg1, eg0, fg1 * eg1) + fmaf(L1f - fk1, ek0, fk1 * ek1)
           + fmaf(L1f - fp1, er0, fp1 * er1);
        if (h) { A0 = 0.f; A1 = 0.f; }
    }
    {
        // h=0: job(11)+rep(34) over hist[0..44]; h=1: place(19)+add(31) over hist[45..94]
        const float* tA = h ? emb_pl : emb_j;
        const float* tB = h ? emb_a  : emb_r;
        const int nA = h ? 19 : 11;
        const int nT = h ? 50 : 45;
        const int hb = h ? 45 : 0;
        #pragma unroll 5
        for (int r = 0; r < nT; ++r) {
            const float* p = (r < nA) ? (tA + (r << 5)) : (tB + ((r - nA) << 5));
            float w = p[ch];
            A0 = fmaf((float)hist[0][hb + r], w, A0);
            A1 = fmaf((float)hist[1][hb + r], w, A1);
        }
        const float sc = h ? 0.5f : 0.2f;
        sPool[0][(h << 5) + ch] = A0 * (invL0 * sc);
        sPool[1][(h << 5) + ch] = A1 * (invL1 * sc);
    }
    {
        // unified 32x32 second layer, dual-row: one weight load -> 2 FMAs
        const float* W2 = h ? w_c2 : w_p2;
        const float* a0 = &sAcc[0][h << 5];
        const float* a1 = &sAcc[1][h << 5];
        float v0 = bias2, v1 = bias2;
        #pragma unroll 8
        for (int k = 0; k < 32; ++k) {
            float w = W2[(k << 5) + ch];
            v0 = fmaf(a0[k], w, v0);
            v1 = fmaf(a1[k], w, v1);
        }
        sPool[0][64 + (h << 5) + ch] = v0;
        sPool[1][64 + (h << 5) + ch] = v1;
    }
    __syncthreads();   // sPool ready

    // ---- fc1 (one output per lane, dual-row, global weights) + fc2 ----
    {
        const float* P0 = sPool[0];
        const float* P1 = sPool[1];
        float x0 = bf1, y0 = 0.f, x1 = bf1, y1 = 0.f;
        #pragma unroll 8
        for (int k = 0; k < 128; k += 2) {
            float w0 = w_fc1[(size_t)k * 64 + lane];
            float w1 = w_fc1[(size_t)(k + 1) * 64 + lane];
            float2 u0 = *(const float2*)&P0[k];
            float2 u1 = *(const float2*)&P1[k];
            x0 = fmaf(u0.x, w0, x0); y0 = fmaf(u0.y, w1, y0);
            x1 = fmaf(u1.x, w0, x1); y1 = fmaf(u1.y, w1, y1);
        }
        float h0v = fmaxf(x0 + y0, 0.f);
        float h1v = fmaxf(x1 + y1, 0.f);
        float q00 = h0v * wf2.x, q01 = h0v * wf2.y;
        float q10 = h1v * wf2.x, q11 = h1v * wf2.y;
        #pragma unroll
        for (int d = 32; d; d >>= 1) {
            q00 += __shfl_xor(q00, d); q01 += __shfl_xor(q01, d);
            q10 += __shfl_xor(q10, d); q11 += __shfl_xor(q11, d);
        }
        if (lane == 0) {
            float4 o4;
            o4.x = fmaxf(q00 + bq0, 0.f);
            o4.y = fmaxf(q01 + bq1, 0.f);
            o4.z = fmaxf(q10 + bq0, 0.f);
            o4.w = fmaxf(q11 + bq1, 0.f);
            *(float4*)&out[(size_t)b0 * 2] = o4;   // rows b0,b1; 16B-aligned
        }
    }
}

extern "C" void kernel_launch(void* const* d_in, const int* in_sizes, int n_in,
                              void* d_out, int out_size, void* d_ws, size_t ws_size,
                              hipStream_t stream) {
    const float* cont_p = (const float*)d_in[0];
    const float* cont_c = (const float*)d_in[1];
    const int*   cat_p  = (const int*)d_in[2];
    const int*   cat_c  = (const int*)d_in[3];
    const int*   lens   = (const int*)d_in[4];
    const float* w_p1   = (const float*)d_in[5];
    const float* b_p1   = (const float*)d_in[6];
    const float* w_p2   = (const float*)d_in[7];
    const float* b_p2   = (const float*)d_in[8];
    const float* w_c1   = (const float*)d_in[9];
    const float* b_c1   = (const float*)d_in[10];
    const float* w_c2   = (const float*)d_in[11];
    const float* b_c2   = (const float*)d_in[12];
    const float* emb_g  = (const float*)d_in[13];
    const float* emb_k  = (const float*)d_in[14];
    const float* emb_pr = (const float*)d_in[15];
    const float* emb_j  = (const float*)d_in[16];
    const float* emb_r  = (const float*)d_in[17];
    const float* emb_pl = (const float*)d_in[18];
    const float* emb_a  = (const float*)d_in[19];
    const float* w_fc1  = (const float*)d_in[20];
    const float* b_fc1  = (const float*)d_in[21];
    const float* w_fc2  = (const float*)d_in[22];
    const float* b_fc2  = (const float*)d_in[23];
    float* out = (float*)d_out;

    hipLaunchKernelGGL(mlpreg_kernel, dim3(2048), dim3(BDIM), 0, stream,
                       cont_p, cont_c, cat_p, cat_c, lens,
                       w_p1, b_p1, w_p2, b_p2, w_c1, b_c1, w_c2, b_c2,
                       emb_g, emb_k, emb_pr, emb_j, emb_r, emb_pl, emb_a,
                       w_fc1, b_fc1, w_fc2, b_fc2, out);
}

// Round 7
// 141.067 us; speedup vs baseline: 1.0857x; 1.0171x over previous
//
#include <hip/hip_runtime.h>

// R14: ONE ROW PER WAVE, everything staged. 4096 x 64, 16 WGs/CU (10.0 KB
// LDS exactly -> 16 x 10240 = 160 KiB), 4 waves/SIMD.
// Theory: staged-cont kernels (R8/R11b/R13) all pin at ~31us with IDENTICAL
// per-wave work (2 rows/wave); direct-global ones pin at 43. VALUBusy ~20%,
// HBM 4% -> latency-exposed per-wave chain, never enough TLP to hide it.
// This is the clean discriminating cell never run: staged + half the
// per-wave work + double the waves/CU.
//  - cont_p, cont_c, AND cat_p staged via global_load_lds w=16 (cat in LDS
//    also removes the compiler-sinks-register-loads doubt: gld16 is
//    fire-and-forget, guaranteed in flight until the vmcnt drain)
//  - token loop: contiguous half-wave split of 4-token groups (<=32 iters
//    per half), one shfl_xor(32) combine
//  - cat from LDS with R12's mod-5 field attribution (single row)
//  - hist/sAcc/sPool ALIASED into consumed cont regions (extra barrier as
//    compiler fence) -> LDS exactly 10240 B
// Algebra unchanged: histogram-weighted table sums, binary-vocab counts =
// index sums, pooling commutes with the 32x32 second layers.

#define BDIM 64

__device__ __forceinline__ void gld16(const void* g, void* l) {
    __builtin_amdgcn_global_load_lds((__attribute__((address_space(1))) void*)g,
                                     (__attribute__((address_space(3))) void*)l,
                                     16, 0, 0);
}

__global__ __launch_bounds__(BDIM)
void mlpreg_kernel(const float* __restrict__ cont_p,
                   const float* __restrict__ cont_c,
                   const int* __restrict__ cat_p,
                   const int* __restrict__ cat_c,
                   const int* __restrict__ lengths,
                   const float* __restrict__ w_p1, const float* __restrict__ b_p1,
                   const float* __restrict__ w_p2, const float* __restrict__ b_p2,
                   const float* __restrict__ w_c1, const float* __restrict__ b_c1,
                   const float* __restrict__ w_c2, const float* __restrict__ b_c2,
                   const float* __restrict__ emb_g,  const float* __restrict__ emb_k,
                   const float* __restrict__ emb_pr, const float* __restrict__ emb_j,
                   const float* __restrict__ emb_r,  const float* __restrict__ emb_pl,
                   const float* __restrict__ emb_a,
                   const float* __restrict__ w_fc1, const float* __restrict__ b_fc1,
                   const float* __restrict__ w_fc2, const float* __restrict__ b_fc2,
                   float* __restrict__ out)
{
    constexpr int S = 256;
    // 10240 B total. Layout: [0..767] cont_p row | [768..1279] cont_c row |
    // [1280..2559] cat_p row (1280 ints). After consumption, aliased:
    // hist -> sBuf[0..95] (ints), sAcc -> sBuf[768..831], sPool -> sBuf[832..959].
    __shared__ __align__(16) float sBuf[2560];
    float* sPc  = sBuf;
    float* sCc  = sBuf + 768;
    int*   sKp  = (int*)(sBuf + 1280);
    int*   hist = (int*)sBuf;          // valid after B2
    float* sAcc = sBuf + 768;          // written at token-loop end
    float* sPool = sBuf + 832;         // written in tail

    const int lane = threadIdx.x;
    const int ch = lane & 31, h = lane >> 5;
    const int b = blockIdx.x;

    int L = lengths[b]; L = (L < 1) ? 1 : (L > S ? S : L);
    const float Lf = (float)L, invL = 1.0f / Lf;

    // ---- staging: global_load_lds 16B, wave-uniform chunk gating ----
    {
        const char* gp = (const char*)(cont_p + (size_t)b * 768);
        const char* gc = (const char*)(cont_c + (size_t)b * 512);
        const char* gk = (const char*)(cat_p + (size_t)b * 1280);
        const int lo = 16 * lane;
        const int bP = 12 * L, bC = 8 * L, bK = 20 * L;
        gld16(gp + lo, (char*)sPc);
        if (1024 < bP) gld16(gp + 1024 + lo, (char*)sPc + 1024);
        if (2048 < bP) gld16(gp + 2048 + lo, (char*)sPc + 2048);
        gld16(gc + lo, (char*)sCc);
        if (1024 < bC) gld16(gc + 1024 + lo, (char*)sCc + 1024);
        #pragma unroll
        for (int j = 0; j < 5; ++j)
            if (1024 * j < bK) gld16(gk + 1024 * j + lo, (char*)sKp + 1024 * j);
    }
    // cat_c: 2 predicated int4 register loads (consumed late; latency hidden)
    const int limc = 2 * L;
    const int4* KC = (const int4*)(cat_c + (size_t)b * 512);
    int4 qc0, qc1;
    const bool hc0 = (4 * lane < limc), hc1 = (256 + 4 * lane < limc);
    if (hc0) qc0 = KC[lane];
    if (hc1) qc1 = KC[lane + 64];

    // ---- small-weight register preloads (issue under staging latency) ----
    const float wp0 = w_p1[ch], wp1 = w_p1[32 + ch], wp2 = w_p1[64 + ch], bp = b_p1[ch];
    const float wc0 = w_c1[ch], wc1 = w_c1[32 + ch], bc = b_c1[ch];
    const float eg0 = emb_g[ch],  eg1 = emb_g[32 + ch];
    const float ek0 = emb_k[ch],  ek1 = emb_k[32 + ch];
    const float er0 = emb_pr[ch], er1 = emb_pr[32 + ch];
    const float bias2 = h ? b_c2[ch] : b_p2[ch];
    const float bf1 = b_fc1[lane];
    const float2 wf2 = *(const float2*)&w_fc2[2 * lane];
    const float bq0 = b_fc2[0], bq1 = b_fc2[1];

    __syncthreads();   // B1: vmcnt drain -> all staged data in LDS

    // ---- token relu-MLP: contiguous half-wave split of 4-token groups ----
    float aP = 0.f, aC = 0.f;
    {
        const int gf = L >> 2;            // full 4-token groups
        const int gh = (gf + 1) >> 1;     // h=0 takes [0,gh), h=1 takes [gh,gf)
        const float4* tp4 = (const float4*)sPc;
        const float4* tc4 = (const float4*)sCc;
        #pragma unroll 4
        for (int i = 0; i < gh; ++i) {
            const int g = h ? gh + i : i;
            if (g < gf) {
                float4 a  = tp4[3 * g], bb = tp4[3 * g + 1], cc = tp4[3 * g + 2];
                float4 d  = tc4[2 * g], ee = tc4[2 * g + 1];
                float p0 = fmaxf(fmaf(a.x,  wp0, fmaf(a.y,  wp1, fmaf(a.z,  wp2, bp))), 0.f);
                float p1 = fmaxf(fmaf(a.w,  wp0, fmaf(bb.x, wp1, fmaf(bb.y, wp2, bp))), 0.f);
                float p2 = fmaxf(fmaf(bb.z, wp0, fmaf(bb.w, wp1, fmaf(cc.x, wp2, bp))), 0.f);
                float p3 = fmaxf(fmaf(cc.y, wp0, fmaf(cc.z, wp1, fmaf(cc.w, wp2, bp))), 0.f);
                aP += (p0 + p1) + (p2 + p3);
                float q0 = fmaxf(fmaf(d.x,  wc0, fmaf(d.y,  wc1, bc)), 0.f);
                float q1 = fmaxf(fmaf(d.z,  wc0, fmaf(d.w,  wc1, bc)), 0.f);
                float q2 = fmaxf(fmaf(ee.x, wc0, fmaf(ee.y, wc1, bc)), 0.f);
                float q3 = fmaxf(fmaf(ee.z, wc0, fmaf(ee.w, wc1, bc)), 0.f);
                aC += (q0 + q1) + (q2 + q3);
            }
        }
        const int rem = L & 3;
        if (h == 0 && rem) {
            const float* tp = sPc + 12 * gf;
            const float* tc = sCc + 8 * gf;
            for (int r = 0; r < rem; ++r) {
                aP += fmaxf(fmaf(tp[3*r], wp0, fmaf(tp[3*r+1], wp1, fmaf(tp[3*r+2], wp2, bp))), 0.f);
                aC += fmaxf(fmaf(tc[2*r], wc0, fmaf(tc[2*r+1], wc1, bc)), 0.f);
            }
        }
        aP += __shfl_xor(aP, 32);
        aC += __shfl_xor(aC, 32);
        sAcc[lane] = (h ? aC : aP) * invL;   // aliases sCc start: reads done
    }
    __syncthreads();   // B2: fence -> hist may now overwrite cont_p region

    // ---- hist zero (aliased over consumed cont_p) ----
    hist[lane] = 0;
    if (lane < 32) hist[64 + lane] = 0;

    // ---- cat_p from LDS: per-lane int4, mod-5 field attribution ----
    int sg = 0, sk = 0, sp = 0;
    {
        const int limp = 5 * L;
        const int m0 = (lane << 2) % 5;
        #pragma unroll
        for (int j = 0; j < 5; ++j) {
            if (256 * j < limp) {
                int4 v4 = ((const int4*)sKp)[lane + 64 * j];
                const int base = 4 * lane + 256 * j;
                int mj = m0 + j; if (mj >= 5) mj -= 5;
                const int v[4] = {v4.x, v4.y, v4.z, v4.w};
                #pragma unroll
                for (int c = 0; c < 4; ++c) {
                    int f = mj + c; if (f >= 5) f -= 5;
                    const bool val = (base + c) < limp;
                    const int vv = v[c];
                    sg += (val && f == 0) ? vv : 0;
                    sk += (val && f == 1) ? vv : 0;
                    sp += (val && f == 2) ? vv : 0;
                    if (val && f >= 3) atomicAdd(&hist[(f == 4 ? 11 : 0) + vv], 1);
                }
            }
        }
        // cat_c from registers: even elem -> place, odd -> add
        if (hc0) {
            atomicAdd(&hist[45 + qc0.x], 1);
            if (4 * lane + 1 < limc) atomicAdd(&hist[64 + qc0.y], 1);
            if (4 * lane + 2 < limc) atomicAdd(&hist[45 + qc0.z], 1);
            if (4 * lane + 3 < limc) atomicAdd(&hist[64 + qc0.w], 1);
        }
        if (hc1) {
            atomicAdd(&hist[45 + qc1.x], 1);
            if (257 + 4 * lane < limc) atomicAdd(&hist[64 + qc1.y], 1);
            if (258 + 4 * lane < limc) atomicAdd(&hist[45 + qc1.z], 1);
            if (259 + 4 * lane < limc) atomicAdd(&hist[64 + qc1.w], 1);
        }
    }
    #pragma unroll
    for (int d = 32; d; d >>= 1) {
        sg += __shfl_xor(sg, d); sk += __shfl_xor(sk, d); sp += __shfl_xor(sp, d);
    }

    // ---- tail: unified halves (h=0 p-side, h=1 c-side), single row ----
    float A;
    {
        float fg = (float)sg, fk = (float)sk, fp = (float)sp;
        A = fmaf(Lf - fg, eg0, fg * eg1) + fmaf(Lf - fk, ek0, fk * ek1)
          + fmaf(Lf - fp, er0, fp * er1);
        A = h ? 0.f : A;
    }
    {
        // h=0: job(11)+rep(34) over hist[0..44]; h=1: place(19)+add(31) over hist[45..94]
        const float* tA = h ? emb_pl : emb_j;
        const float* tB = h ? emb_a  : emb_r;
        const int nA = h ? 19 : 11;
        const int nT = h ? 50 : 45;
        const int hb = h ? 45 : 0;
        #pragma unroll 5
        for (int r = 0; r < nT; ++r) {
            const float* p = (r < nA) ? (tA + (r << 5)) : (tB + ((r - nA) << 5));
            A = fmaf((float)hist[hb + r], p[ch], A);
        }
        sPool[(h << 5) + ch] = A * (invL * (h ? 0.5f : 0.2f));
    }
    {
        // unified 32x32 second layer (global weights: proven neutral in R10)
        const float* W2 = h ? w_c2 : w_p2;
        const float* acc = sAcc + (h << 5);
        float v = bias2;
        #pragma unroll 8
        for (int k = 0; k < 32; ++k)
            v = fmaf(acc[k], W2[(k << 5) + ch], v);
        sPool[64 + (h << 5) + ch] = v;
    }

    // ---- fc1 (one output per lane) + fc2 butterfly ----
    {
        float x = bf1, y = 0.f;
        #pragma unroll 8
        for (int k = 0; k < 128; k += 2) {
            float w0 = w_fc1[(size_t)k * 64 + lane];
            float w1 = w_fc1[(size_t)(k + 1) * 64 + lane];
            float2 u = *(const float2*)&sPool[k];
            x = fmaf(u.x, w0, x); y = fmaf(u.y, w1, y);
        }
        float hv = fmaxf(x + y, 0.f);
        float q0 = hv * wf2.x, q1 = hv * wf2.y;
        #pragma unroll
        for (int d = 32; d; d >>= 1) {
            q0 += __shfl_xor(q0, d); q1 += __shfl_xor(q1, d);
        }
        if (lane == 0) {
            float2 o2;
            o2.x = fmaxf(q0 + bq0, 0.f);
            o2.y = fmaxf(q1 + bq1, 0.f);
            *(float2*)&out[(size_t)b * 2] = o2;   // 8B-aligned per-row store
        }
    }
}

extern "C" void kernel_launch(void* const* d_in, const int* in_sizes, int n_in,
                              void* d_out, int out_size, void* d_ws, size_t ws_size,
                              hipStream_t stream) {
    const float* cont_p = (const float*)d_in[0];
    const float* cont_c = (const float*)d_in[1];
    const int*   cat_p  = (const int*)d_in[2];
    const int*   cat_c  = (const int*)d_in[3];
    const int*   lens   = (const int*)d_in[4];
    const float* w_p1   = (const float*)d_in[5];
    const float* b_p1   = (const float*)d_in[6];
    const float* w_p2   = (const float*)d_in[7];
    const float* b_p2   = (const float*)d_in[8];
    const float* w_c1   = (const float*)d_in[9];
    const float* b_c1   = (const float*)d_in[10];
    const float* w_c2   = (const float*)d_in[11];
    const float* b_c2   = (const float*)d_in[12];
    const float* emb_g  = (const float*)d_in[13];
    const float* emb_k  = (const float*)d_in[14];
    const float* emb_pr = (const float*)d_in[15];
    const float* emb_j  = (const float*)d_in[16];
    const float* emb_r  = (const float*)d_in[17];
    const float* emb_pl = (const float*)d_in[18];
    const float* emb_a  = (const float*)d_in[19];
    const float* w_fc1  = (const float*)d_in[20];
    const float* b_fc1  = (const float*)d_in[21];
    const float* w_fc2  = (const float*)d_in[22];
    const float* b_fc2  = (const float*)d_in[23];
    float* out = (float*)d_out;

    hipLaunchKernelGGL(mlpreg_kernel, dim3(4096), dim3(BDIM), 0, stream,
                       cont_p, cont_c, cat_p, cat_c, lens,
                       w_p1, b_p1, w_p2, b_p2, w_c1, b_c1, w_c2, b_c2,
                       emb_g, emb_k, emb_pr, emb_j, emb_r, emb_pl, emb_a,
                       w_fc1, b_fc1, w_fc2, b_fc2, out);
}